// Round 14
// baseline (336.036 us; speedup 1.0000x reference)
//
#include <hip/hip_runtime.h>
#include <math.h>
#include <type_traits>

// ---------------------------------------------------------------------------
// NodeClsGAT: 3-layer GATConv (single head, PyG defaults) on MI355X.
// CSR build via 2-level bucket sort (R2, bscan eliminated R14 — bscatter/bcsr
// recompute the 196-bucket scan locally from bcount; gcur is a zero-init
// cursor). GEMM via MFMA 16x16x32_f16 (R10); gemm1 fused with hist (R13).
// k_agg: R10 two-phase (R11's in-loop load fusion regressed). R14: gemm3
// fused into agg2 (k_aggf) — W3 staged in LDS, per-node 64x10 matvec in the
// epilogue, writes fp16 hC + layer-3 alphas to SEPARATE asb3/adb3 buffers.
// ---------------------------------------------------------------------------

#define NEG_SLOPE 0.2f
#define BKT_BITS 9          // 512 nodes per bucket; supports N <= 262144
#define BKT_SZ   512
#define PACK_SRC_BITS 20    // src < 2^20 (N = 100000)

typedef _Float16 h8v __attribute__((ext_vector_type(8)));
typedef _Float16 h4v __attribute__((ext_vector_type(4)));
typedef float f4v __attribute__((ext_vector_type(4)));

// ---------------- pass B — rank-scatter packed records into buckets -----
// R14: local exclusive scan of bcount (first 512 threads) replaces k_bscan;
// gcur is a zero-initialized cursor, write base = excl_scan + atomicAdd.
__global__ __launch_bounds__(1024) void k_bscatter(const int* __restrict__ src,
                                                   const int* __restrict__ dst, int E,
                                                   int nb,
                                                   const int* __restrict__ bcount,
                                                   int* __restrict__ gcur,
                                                   int* __restrict__ ebuf) {
    __shared__ int lc[BKT_SZ];
    __shared__ int gb[BKT_SZ];
    __shared__ int sc[BKT_SZ];
    int t = threadIdx.x;
    for (int i = t; i < nb; i += 1024) lc[i] = 0;
    __syncthreads();
    int base = blockIdx.x * 8192;
    int bkt[8], rnk[8], pk[8];
#pragma unroll
    for (int j = 0; j < 8; j++) {
        int i = base + j * 1024 + t;
        bkt[j] = -1;
        if (i < E) {
            int d = dst[i];
            int s = src[i];
            int b = d >> BKT_BITS;
            bkt[j] = b;
            rnk[j] = atomicAdd(&lc[b], 1);
            pk[j] = ((d & (BKT_SZ - 1)) << PACK_SRC_BITS) | s;
        }
    }
    __syncthreads();
    // inclusive scan of bcount in sc (512-wide, all threads hit barriers)
    if (t < BKT_SZ) sc[t] = (t < nb) ? bcount[t] : 0;
    __syncthreads();
    for (int o = 1; o < BKT_SZ; o <<= 1) {
        int tv = (t < BKT_SZ && t >= o) ? sc[t - o] : 0;
        __syncthreads();
        if (t < BKT_SZ) sc[t] += tv;
        __syncthreads();
    }
    for (int b = t; b < nb; b += 1024)
        if (lc[b]) gb[b] = (sc[b] - bcount[b]) + atomicAdd(&gcur[b], lc[b]);
    __syncthreads();
#pragma unroll
    for (int j = 0; j < 8; j++)
        if (bkt[j] >= 0) ebuf[gb[bkt[j]] + rnk[j]] = pk[j];
}

// ---------------- pass C — per-bucket CSR finalize ----------------------
// R14: recomputes the bucket scan locally (e0/e1) instead of reading ebase.
__global__ __launch_bounds__(512) void k_bcsr(const int* __restrict__ ebuf,
                                              const int* __restrict__ bcount, int nb,
                                              int E, int N,
                                              int* __restrict__ rowptr,
                                              int* __restrict__ csr) {
    __shared__ int cnt[BKT_SZ];
    __shared__ int sm[BKT_SZ];
    int b = blockIdx.x;
    int t = threadIdx.x;
    // scan bcount (inclusive) -> e0,e1 for this block's bucket
    sm[t] = (t < nb) ? bcount[t] : 0;
    __syncthreads();
    for (int o = 1; o < BKT_SZ; o <<= 1) {
        int tv = (t >= o) ? sm[t - o] : 0;
        __syncthreads();
        sm[t] += tv;
        __syncthreads();
    }
    int e1 = sm[b];
    int e0 = e1 - bcount[b];
    if (b == 0 && t == 0) rowptr[N] = E + N;
    __syncthreads();  // done with sm's scan values

    int n0 = b << BKT_BITS;
    int nn = min(BKT_SZ, N - n0);
    cnt[t] = 0;
    __syncthreads();
    for (int i = e0 + t; i < e1; i += BKT_SZ)
        atomicAdd(&cnt[ebuf[i] >> PACK_SRC_BITS], 1);
    __syncthreads();
    int v = cnt[t] + (t < nn ? 1 : 0);  // +1 self-loop slot per valid node
    sm[t] = v;
    __syncthreads();
    for (int o = 1; o < BKT_SZ; o <<= 1) {
        int tv = (t >= o) ? sm[t - o] : 0;
        __syncthreads();
        sm[t] += tv;
        __syncthreads();
    }
    int excl = sm[t] - v;
    int cb = e0 + n0;  // csr base: edges before bucket + self-loops before bucket
    if (t < nn) {
        rowptr[n0 + t] = cb + excl;
        csr[cb + excl] = n0 + t;  // self-loop at slot 0 of the node's segment
    }
    cnt[t] = excl + 1;  // edge cursor (after self-loop)
    __syncthreads();
    for (int i = e0 + t; i < e1; i += BKT_SZ) {
        int p = ebuf[i];
        int dl = p >> PACK_SRC_BITS;
        int pos = atomicAdd(&cnt[dl], 1);
        csr[cb + pos] = p & ((1 << PACK_SRC_BITS) - 1);
    }
}

// ---------------- GEMM body (FP=64, Freal=64) via MFMA, inlinable ----------
__device__ __forceinline__ void gemm64_body(
    int bid, int nblocks, const float* __restrict__ X, const float* __restrict__ W,
    const float* __restrict__ a_s, const float* __restrict__ a_d, int N,
    _Float16* __restrict__ H, float* __restrict__ asb, float* __restrict__ adb) {
    constexpr int NT = 4;
    int lane = threadIdx.x & 63;
    int quad = lane >> 4;
    int c16 = lane & 15;

    h8v bf[NT][2];
    float asv[NT], adv[NT];
#pragma unroll
    for (int nt = 0; nt < NT; nt++) {
        int n = nt * 16 + c16;
        asv[nt] = a_s[n];
        adv[nt] = a_d[n];
#pragma unroll
        for (int kt = 0; kt < 2; kt++)
#pragma unroll
            for (int j = 0; j < 8; j++) {
                int k = kt * 32 + quad * 8 + j;
                bf[nt][kt][j] = (_Float16)W[k * 64 + n];
            }
    }

    int wid = (bid * 256 + (int)threadIdx.x) >> 6;
    int nw = (nblocks * 256) >> 6;
    int ntile = (N + 15) >> 4;

    for (int t = wid; t < ntile; t += nw) {
        int m0 = t << 4;
        int row = m0 + c16;
        const float* xr = X + (size_t)min(row, N - 1) * 64;
        h8v af[2];
#pragma unroll
        for (int kt = 0; kt < 2; kt++) {
            f4v x0 = *(const f4v*)(xr + kt * 32 + quad * 8);
            f4v x1 = *(const f4v*)(xr + kt * 32 + quad * 8 + 4);
#pragma unroll
            for (int j = 0; j < 4; j++) {
                af[kt][j] = (_Float16)x0[j];
                af[kt][4 + j] = (_Float16)x1[j];
            }
        }
        f4v c[NT];
#pragma unroll
        for (int nt = 0; nt < NT; nt++) c[nt] = (f4v){0.f, 0.f, 0.f, 0.f};
#pragma unroll
        for (int kt = 0; kt < 2; kt++)
#pragma unroll
            for (int nt = 0; nt < NT; nt++)
                c[nt] = __builtin_amdgcn_mfma_f32_16x16x32_f16(af[kt], bf[nt][kt],
                                                               c[nt], 0, 0, 0);
#pragma unroll
        for (int reg = 0; reg < 4; reg++) {
            int r = m0 + quad * 4 + reg;
            if (r < N) {
#pragma unroll
                for (int nt = 0; nt < NT; nt++)
                    H[(size_t)r * 64 + nt * 16 + c16] = (_Float16)c[nt][reg];
            }
        }
        float ps[4], pd[4];
#pragma unroll
        for (int reg = 0; reg < 4; reg++) {
            ps[reg] = 0.f;
            pd[reg] = 0.f;
#pragma unroll
            for (int nt = 0; nt < NT; nt++) {
                ps[reg] = fmaf(c[nt][reg], asv[nt], ps[reg]);
                pd[reg] = fmaf(c[nt][reg], adv[nt], pd[reg]);
            }
        }
        for (int o = 1; o < 16; o <<= 1) {
#pragma unroll
            for (int reg = 0; reg < 4; reg++) {
                ps[reg] += __shfl_xor(ps[reg], o, 64);
                pd[reg] += __shfl_xor(pd[reg], o, 64);
            }
        }
        if (c16 == 0) {
#pragma unroll
            for (int reg = 0; reg < 4; reg++) {
                int r = m0 + quad * 4 + reg;
                if (r < N) {
                    asb[r] = ps[reg];
                    adb[r] = pd[reg];
                }
            }
        }
    }
}

// ---------------- fused: bucket histogram + layer-1 GEMM -------------------
__global__ __launch_bounds__(256) void k_hist_gemm(
    const int* __restrict__ dst, int E, int nb, int* __restrict__ bcount,
    int histBlocks,
    const float* __restrict__ X, const float* __restrict__ W,
    const float* __restrict__ a_s, const float* __restrict__ a_d, int N,
    _Float16* __restrict__ H, float* __restrict__ asb, float* __restrict__ adb) {
    __shared__ int h[BKT_SZ];
    int bid = blockIdx.x;
    if (bid < histBlocks) {
        for (int i = threadIdx.x; i < nb; i += 256) h[i] = 0;
        __syncthreads();
        for (int i = bid * 256 + threadIdx.x; i < E; i += histBlocks * 256)
            atomicAdd(&h[dst[i] >> BKT_BITS], 1);
        __syncthreads();
        for (int i = threadIdx.x; i < nb; i += 256)
            if (h[i]) atomicAdd(&bcount[i], h[i]);
    } else {
        gemm64_body(bid - histBlocks, (int)gridDim.x - histBlocks, X, W, a_s, a_d,
                    N, H, asb, adb);
    }
}

// ---------------- standalone GEMM (layer 2) --------------------------------
template <int FP>
__global__ __launch_bounds__(256) void k_gemm(
    const float* __restrict__ X, const float* __restrict__ W,
    const float* __restrict__ a_s, const float* __restrict__ a_d,
    int N, int Freal,
    _Float16* __restrict__ H, float* __restrict__ asb, float* __restrict__ adb) {
    constexpr int NT = FP / 16;
    int lane = threadIdx.x & 63;
    int quad = lane >> 4;
    int c16 = lane & 15;

    h8v bf[NT][2];
    float asv[NT], adv[NT];
#pragma unroll
    for (int nt = 0; nt < NT; nt++) {
        int n = nt * 16 + c16;
        bool ok = (n < Freal);
        asv[nt] = ok ? a_s[n] : 0.f;
        adv[nt] = ok ? a_d[n] : 0.f;
#pragma unroll
        for (int kt = 0; kt < 2; kt++)
#pragma unroll
            for (int j = 0; j < 8; j++) {
                int k = kt * 32 + quad * 8 + j;
                bf[nt][kt][j] = (_Float16)(ok ? W[k * Freal + n] : 0.f);
            }
    }

    int wid = (blockIdx.x * blockDim.x + threadIdx.x) >> 6;
    int nw = (gridDim.x * blockDim.x) >> 6;
    int ntile = (N + 15) >> 4;

    for (int t = wid; t < ntile; t += nw) {
        int m0 = t << 4;
        int row = m0 + c16;
        const float* xr = X + (size_t)min(row, N - 1) * 64;
        h8v af[2];
#pragma unroll
        for (int kt = 0; kt < 2; kt++) {
            f4v x0 = *(const f4v*)(xr + kt * 32 + quad * 8);
            f4v x1 = *(const f4v*)(xr + kt * 32 + quad * 8 + 4);
#pragma unroll
            for (int j = 0; j < 4; j++) {
                af[kt][j] = (_Float16)x0[j];
                af[kt][4 + j] = (_Float16)x1[j];
            }
        }
        f4v c[NT];
#pragma unroll
        for (int nt = 0; nt < NT; nt++) c[nt] = (f4v){0.f, 0.f, 0.f, 0.f};
#pragma unroll
        for (int kt = 0; kt < 2; kt++)
#pragma unroll
            for (int nt = 0; nt < NT; nt++)
                c[nt] = __builtin_amdgcn_mfma_f32_16x16x32_f16(af[kt], bf[nt][kt],
                                                               c[nt], 0, 0, 0);
#pragma unroll
        for (int reg = 0; reg < 4; reg++) {
            int r = m0 + quad * 4 + reg;
            if (r < N) {
#pragma unroll
                for (int nt = 0; nt < NT; nt++)
                    H[(size_t)r * FP + nt * 16 + c16] = (_Float16)c[nt][reg];
            }
        }
        float ps[4], pd[4];
#pragma unroll
        for (int reg = 0; reg < 4; reg++) {
            ps[reg] = 0.f;
            pd[reg] = 0.f;
#pragma unroll
            for (int nt = 0; nt < NT; nt++) {
                ps[reg] = fmaf(c[nt][reg], asv[nt], ps[reg]);
                pd[reg] = fmaf(c[nt][reg], adv[nt], pd[reg]);
            }
        }
        for (int o = 1; o < 16; o <<= 1) {
#pragma unroll
            for (int reg = 0; reg < 4; reg++) {
                ps[reg] += __shfl_xor(ps[reg], o, 64);
                pd[reg] += __shfl_xor(pd[reg], o, 64);
            }
        }
        if (c16 == 0) {
#pragma unroll
            for (int reg = 0; reg < 4; reg++) {
                int r = m0 + quad * 4 + reg;
                if (r < N) {
                    asb[r] = ps[reg];
                    adb[r] = pd[reg];
                }
            }
        }
    }
}

// ---------------- slow-path agg (R4-proven, whole wave, any deg) -----------
template <int FP>
__device__ __forceinline__ void agg_slow(
    int node, const _Float16* __restrict__ H, const float* __restrict__ asb,
    const float* __restrict__ adb, const float* __restrict__ bias,
    const int* __restrict__ rowptr, const int* __restrict__ csr,
    int N, int Freal, float* __restrict__ out, int mode, int lane) {
    if (node >= N) return;
    int start = rowptr[node];
    int end = rowptr[node + 1];
    float ad = adb[node];
    int lf = lane & (FP - 1);
    const float NEG_INF = -__builtin_inff();

    float m = NEG_INF;
    for (int base = start; base < end; base += 64) {
        int i = base + lane;
        if (i < end) {
            float t = asb[csr[i]] + ad;
            float e = (t > 0.f) ? t : NEG_SLOPE * t;
            m = fmaxf(m, e);
        }
    }
    for (int o = 32; o > 0; o >>= 1) m = fmaxf(m, __shfl_xor(m, o, 64));
    float dsum = 0.f, acc = 0.f;
    for (int base = start; base < end; base += 64) {
        int i = base + lane;
        int cnt = min(64, end - base);
        int s = 0;
        float p = 0.f;
        if (i < end) {
            s = csr[i];
            float t = asb[s] + ad;
            float e = (t > 0.f) ? t : NEG_SLOPE * t;
            p = __expf(e - m);
        }
        dsum += p;
        for (int j = 0; j < cnt; j++) {
            float pj = __shfl(p, j, 64);
            int sj = __shfl(s, j, 64);
            acc = fmaf(pj, (float)H[(size_t)sj * FP + lf], acc);
        }
    }
    for (int o = 32; o > 0; o >>= 1) dsum += __shfl_xor(dsum, o, 64);

    float b = (lf < Freal) ? bias[lf] : 0.f;
    float z = acc / dsum + b;
    if (mode == 0) {
        if (lane < FP) out[(size_t)node * FP + lane] = fmaxf(z, 0.f);
    } else {
        float zz = (lane < Freal) ? z : NEG_INF;
        float zm = zz;
        for (int o = 32; o > 0; o >>= 1) zm = fmaxf(zm, __shfl_xor(zm, o, 64));
        float ez = (lane < Freal) ? __expf(zz - zm) : 0.f;
        float es = ez;
        for (int o = 32; o > 0; o >>= 1) es += __shfl_xor(es, o, 64);
        if (lane < Freal) out[(size_t)node * Freal + lane] = zz - zm - __logf(es);
    }
}

// slow-path variant returning z = agg + bias (no relu, no store); FP=64 only.
__device__ __forceinline__ float agg_slow_z64(
    int node, const _Float16* __restrict__ H, const float* __restrict__ asb,
    const float* __restrict__ adb, const float* __restrict__ bias,
    const int* __restrict__ rowptr, const int* __restrict__ csr, int lane) {
    int start = rowptr[node];
    int end = rowptr[node + 1];
    float ad = adb[node];
    const float NEG_INF = -__builtin_inff();

    float m = NEG_INF;
    for (int base = start; base < end; base += 64) {
        int i = base + lane;
        if (i < end) {
            float t = asb[csr[i]] + ad;
            float e = (t > 0.f) ? t : NEG_SLOPE * t;
            m = fmaxf(m, e);
        }
    }
    for (int o = 32; o > 0; o >>= 1) m = fmaxf(m, __shfl_xor(m, o, 64));
    float dsum = 0.f, acc = 0.f;
    for (int base = start; base < end; base += 64) {
        int i = base + lane;
        int cnt = min(64, end - base);
        int s = 0;
        float p = 0.f;
        if (i < end) {
            s = csr[i];
            float t = asb[s] + ad;
            float e = (t > 0.f) ? t : NEG_SLOPE * t;
            p = __expf(e - m);
        }
        dsum += p;
        for (int j = 0; j < cnt; j++) {
            float pj = __shfl(p, j, 64);
            int sj = __shfl(s, j, 64);
            acc = fmaf(pj, (float)H[(size_t)sj * 64 + lane], acc);
        }
    }
    for (int o = 32; o > 0; o >>= 1) dsum += __shfl_xor(dsum, o, 64);
    return acc / dsum + bias[lane];
}

// ---------------- Aggregation: dual-node wave, vector gather (R10) ---------
template <int FP, int W>
__global__ __launch_bounds__(256) void k_agg(
    const _Float16* __restrict__ H, const float* __restrict__ asb,
    const float* __restrict__ adb, const float* __restrict__ bias,
    const int* __restrict__ rowptr, const int* __restrict__ csr,
    int N, int Freal, float* __restrict__ out, int mode) {
    constexpr int LPR = FP / W;    // lanes per row (within a half)
    constexpr int GRPH = 32 / LPR; // rows in flight per half
    using vecW = typename std::conditional<W == 8, h8v, h4v>::type;
    int lane = threadIdx.x & 63;
    int half = lane >> 5;
    int li = lane & 31;
    int wid = (blockIdx.x * blockDim.x + threadIdx.x) >> 6;
    int nA = 2 * wid;
    if (nA >= N) return;
    int n = nA + half;
    bool valid = (n < N);
    int start = 0, end = 0;
    float ad = 0.f;
    if (valid) {
        start = rowptr[n];
        end = rowptr[n + 1];
        ad = adb[n];
    }
    int deg = end - start;
    int degm = max(deg, __shfl_xor(deg, 32, 64));  // wave-uniform

    const float NEG_INF = -__builtin_inff();

    if (degm <= 32) {
        int g = li / LPR;   // row-group within half
        int fl = li % LPR;  // vecW slot within row
        int s = 0;
        float e = NEG_INF;
        if (li < deg) {
            s = csr[start + li];
            float t = asb[s] + ad;
            e = (t > 0.f) ? t : NEG_SLOPE * t;
        }
        float m = e;
        for (int o = 16; o > 0; o >>= 1) m = fmaxf(m, __shfl_xor(m, o, 64));
        float p = (li < deg) ? __expf(e - m) : 0.f;
        float dsum = p;
        for (int o = 16; o > 0; o >>= 1) dsum += __shfl_xor(dsum, o, 64);

        float acc[W];
#pragma unroll
        for (int c = 0; c < W; c++) acc[c] = 0.f;
#pragma unroll 4
        for (int jb = 0; jb < degm; jb += GRPH) {  // wave-uniform bound
            int gidx = half * 32 + jb + g;         // in-half, <= half*32+31
            float pj = __shfl(p, gidx, 64);        // 0 for jb+g >= deg
            int sj = __shfl(s, gidx, 64);          // 0 for jb+g >= deg
            vecW r = ((const vecW*)(H + (size_t)sj * FP))[fl];
#pragma unroll
            for (int c = 0; c < W; c++) acc[c] = fmaf(pj, (float)r[c], acc[c]);
        }
        for (int o = LPR; o < 32; o <<= 1) {
#pragma unroll
            for (int c = 0; c < W; c++) acc[c] += __shfl_xor(acc[c], o, 64);
        }
        float inv = 1.f / dsum;
        int fbase = fl * W;

        if (mode == 0) {
            if (valid && li < LPR) {
                float z[W];
#pragma unroll
                for (int c = 0; c < W; c++)
                    z[c] = fmaxf(fmaf(acc[c], inv, bias[fbase + c]), 0.f);
                float4* op = (float4*)(out + (size_t)n * FP + fbase);
#pragma unroll
                for (int q = 0; q < W / 4; q++)
                    op[q] = make_float4(z[4 * q], z[4 * q + 1], z[4 * q + 2],
                                        z[4 * q + 3]);
            }
        } else {
            float zc[W];
#pragma unroll
            for (int c = 0; c < W; c++) {
                int f = fbase + c;
                zc[c] = (f < Freal) ? fmaf(acc[c], inv, bias[f]) : NEG_INF;
            }
            float vm = zc[0];
#pragma unroll
            for (int c = 1; c < W; c++) vm = fmaxf(vm, zc[c]);
            for (int o = 1; o < LPR; o <<= 1) vm = fmaxf(vm, __shfl_xor(vm, o, 64));
            float es = 0.f;
#pragma unroll
            for (int c = 0; c < W; c++) es += __expf(zc[c] - vm);
            for (int o = 1; o < LPR; o <<= 1) es += __shfl_xor(es, o, 64);
            float ls = __logf(es);
            if (valid && li < LPR) {
#pragma unroll
                for (int c = 0; c < W; c++) {
                    int f = fbase + c;
                    if (f < Freal) out[(size_t)n * Freal + f] = zc[c] - vm - ls;
                }
            }
        }
    } else {
        agg_slow<FP>(nA, H, asb, adb, bias, rowptr, csr, N, Freal, out, mode, lane);
        agg_slow<FP>(nA + 1, H, asb, adb, bias, rowptr, csr, N, Freal, out, mode, lane);
    }
}

// ---------------- Fused agg2 + gemm3: k_aggf -------------------------------
// Same dual-node structure as k_agg<64,8>, but the epilogue computes
// h3 = relu(z) @ W3 (W3 staged in LDS) and writes fp16 H3 (16-padded) plus
// layer-3 alphas to asb3/adb3 (separate buffers — asb/adb still being read).
__global__ __launch_bounds__(256) void k_aggf(
    const _Float16* __restrict__ H, const float* __restrict__ asb,
    const float* __restrict__ adb, const float* __restrict__ bias,  // b2
    const int* __restrict__ rowptr, const int* __restrict__ csr, int N,
    const float* __restrict__ W3, const float* __restrict__ a3s,
    const float* __restrict__ a3d,
    _Float16* __restrict__ H3, float* __restrict__ asb3,
    float* __restrict__ adb3) {
    constexpr int LPR = 8, GRPH = 4;
    __shared__ float w3l[640];   // W3 row-major [64][10]
    __shared__ float a3sl[10], a3dl[10];
    for (int i = threadIdx.x; i < 640; i += 256) w3l[i] = W3[i];
    if (threadIdx.x < 10) {
        a3sl[threadIdx.x] = a3s[threadIdx.x];
        a3dl[threadIdx.x] = a3d[threadIdx.x];
    }
    __syncthreads();  // before any early return (all waves reach this)

    int lane = threadIdx.x & 63;
    int half = lane >> 5;
    int li = lane & 31;
    int wid = (blockIdx.x * blockDim.x + threadIdx.x) >> 6;
    int nA = 2 * wid;
    if (nA >= N) return;
    int n = nA + half;
    bool valid = (n < N);
    int start = 0, end = 0;
    float ad = 0.f;
    if (valid) {
        start = rowptr[n];
        end = rowptr[n + 1];
        ad = adb[n];
    }
    int deg = end - start;
    int degm = max(deg, __shfl_xor(deg, 32, 64));

    const float NEG_INF = -__builtin_inff();

    if (degm <= 32) {
        int g = li / LPR;
        int fl = li % LPR;
        int s = 0;
        float e = NEG_INF;
        if (li < deg) {
            s = csr[start + li];
            float t = asb[s] + ad;
            e = (t > 0.f) ? t : NEG_SLOPE * t;
        }
        float m = e;
        for (int o = 16; o > 0; o >>= 1) m = fmaxf(m, __shfl_xor(m, o, 64));
        float p = (li < deg) ? __expf(e - m) : 0.f;
        float dsum = p;
        for (int o = 16; o > 0; o >>= 1) dsum += __shfl_xor(dsum, o, 64);

        float acc[8];
#pragma unroll
        for (int c = 0; c < 8; c++) acc[c] = 0.f;
#pragma unroll 4
        for (int jb = 0; jb < degm; jb += GRPH) {
            int gidx = half * 32 + jb + g;
            float pj = __shfl(p, gidx, 64);
            int sj = __shfl(s, gidx, 64);
            h8v r = ((const h8v*)(H + (size_t)sj * 64))[fl];
#pragma unroll
            for (int c = 0; c < 8; c++) acc[c] = fmaf(pj, (float)r[c], acc[c]);
        }
        for (int o = LPR; o < 32; o <<= 1) {
#pragma unroll
            for (int c = 0; c < 8; c++) acc[c] += __shfl_xor(acc[c], o, 64);
        }
        float inv = 1.f / dsum;
        int fbase = fl * 8;
        // z = relu(agg + b2) for features fbase..fbase+7 (dup across groups)
        float z[8];
#pragma unroll
        for (int c = 0; c < 8; c++)
            z[c] = fmaxf(fmaf(acc[c], inv, bias[fbase + c]), 0.f);
        // h3 partials over this lane's 8 features
        float pt[10];
#pragma unroll
        for (int t = 0; t < 10; t++) pt[t] = 0.f;
#pragma unroll
        for (int c = 0; c < 8; c++) {
            const float* wr = &w3l[(fbase + c) * 10];
            float zv = z[c];
#pragma unroll
            for (int t = 0; t < 10; t++) pt[t] = fmaf(zv, wr[t], pt[t]);
        }
        // butterfly over the 8 fl values (xor 1,2,4 stays in 8-lane coset)
        for (int o = 1; o < 8; o <<= 1) {
#pragma unroll
            for (int t = 0; t < 10; t++) pt[t] += __shfl_xor(pt[t], o, 64);
        }
        if (valid) {
            if (li == 0) {
                h8v hv;
#pragma unroll
                for (int j = 0; j < 8; j++) hv[j] = (_Float16)pt[j];
                *(h8v*)(H3 + (size_t)n * 16) = hv;
                float s3 = 0.f, d3 = 0.f;
#pragma unroll
                for (int t = 0; t < 10; t++) {
                    s3 = fmaf(pt[t], a3sl[t], s3);
                    d3 = fmaf(pt[t], a3dl[t], d3);
                }
                asb3[n] = s3;
                adb3[n] = d3;
            }
            if (li == 8) {  // lanes 8..15 hold the same pt (coset-duplicated)
                h8v hv2 = {};
                hv2[0] = (_Float16)pt[8];
                hv2[1] = (_Float16)pt[9];
                *(h8v*)(H3 + (size_t)n * 16 + 8) = hv2;
            }
        }
    } else {
        // rare slow path: whole-wave per node, z via two-pass, then matvec
        for (int q = 0; q < 2; q++) {
            int node = nA + q;
            if (node >= N) continue;
            float z = agg_slow_z64(node, H, asb, adb, bias, rowptr, csr, lane);
            z = fmaxf(z, 0.f);
            float pt[10];
            const float* wr = &w3l[lane * 10];
#pragma unroll
            for (int t = 0; t < 10; t++) pt[t] = z * wr[t];
            for (int o = 1; o < 64; o <<= 1) {
#pragma unroll
                for (int t = 0; t < 10; t++) pt[t] += __shfl_xor(pt[t], o, 64);
            }
            if (lane == 0) {
                h8v hv;
#pragma unroll
                for (int j = 0; j < 8; j++) hv[j] = (_Float16)pt[j];
                *(h8v*)(H3 + (size_t)node * 16) = hv;
                h8v hv2 = {};
                hv2[0] = (_Float16)pt[8];
                hv2[1] = (_Float16)pt[9];
                *(h8v*)(H3 + (size_t)node * 16 + 8) = hv2;
                float s3 = 0.f, d3 = 0.f;
#pragma unroll
                for (int t = 0; t < 10; t++) {
                    s3 = fmaf(pt[t], a3sl[t], s3);
                    d3 = fmaf(pt[t], a3dl[t], d3);
                }
                asb3[node] = s3;
                adb3[node] = d3;
            }
        }
    }
}

// ---------------------------------------------------------------------------
extern "C" void kernel_launch(void* const* d_in, const int* in_sizes, int n_in,
                              void* d_out, int out_size, void* d_ws, size_t ws_size,
                              hipStream_t stream) {
    const float* x = (const float*)d_in[0];
    const int* ei = (const int*)d_in[1];
    const float* W1 = (const float*)d_in[2];
    const float* a1s = (const float*)d_in[3];
    const float* a1d = (const float*)d_in[4];
    const float* b1 = (const float*)d_in[5];
    const float* W2 = (const float*)d_in[6];
    const float* a2s = (const float*)d_in[7];
    const float* a2d = (const float*)d_in[8];
    const float* b2 = (const float*)d_in[9];
    const float* W3 = (const float*)d_in[10];
    const float* a3s = (const float*)d_in[11];
    const float* a3d = (const float*)d_in[12];
    const float* b3 = (const float*)d_in[13];

    const int N = in_sizes[0] / 64;
    const int E = in_sizes[1] / 2;
    const int Etot = E + N;
    const int nb = (N + BKT_SZ - 1) >> BKT_BITS;  // buckets of 512 nodes
    const int* srcv = ei;
    const int* dstv = ei + E;

    // workspace carve (256B aligned)
    size_t off = 0;
    char* base = (char*)d_ws;
    auto carve = [&](size_t bytes) -> void* {
        void* p = base + off;
        off = (off + bytes + 255) & ~(size_t)255;
        return p;
    };
    int* bcount = (int*)carve((size_t)(nb + 1) * 4);
    int* gcur = (int*)carve((size_t)nb * 4);
    int* rowptr = (int*)carve((size_t)(N + 1) * 4);
    int* csr = (int*)carve((size_t)Etot * 4);
    float* asb = (float*)carve((size_t)N * 4);
    float* adb = (float*)carve((size_t)N * 4);
    float* asb3 = (float*)carve((size_t)N * 4);
    float* adb3 = (float*)carve((size_t)N * 4);
    _Float16* hA = (_Float16*)carve((size_t)N * 64 * 2);  // fp16 H (layers 1,2)
    float* fB = (float*)carve((size_t)N * 64 * 4);        // fp32 agg1 out
    _Float16* hC = (_Float16*)carve((size_t)N * 16 * 2);  // fp16 H (layer 3)
    int* ebuf = (int*)carve((size_t)E * 4);

    const int aggBlocks = (N + 7) / 8;  // 4 waves/block, 2 nodes/wave
    const int gemmBlocks = 784;
    const int histBlocks = 512;

    // ---- CSR build (bucket sort) + layer-1 GEMM fused ----
    hipMemsetAsync(bcount, 0, (size_t)nb * 4, stream);
    hipMemsetAsync(gcur, 0, (size_t)nb * 4, stream);
    k_hist_gemm<<<histBlocks + gemmBlocks, 256, 0, stream>>>(
        dstv, E, nb, bcount, histBlocks, x, W1, a1s, a1d, N, hA, asb, adb);
    k_bscatter<<<(E + 8191) / 8192, 1024, 0, stream>>>(srcv, dstv, E, nb, bcount,
                                                       gcur, ebuf);
    k_bcsr<<<nb, BKT_SZ, 0, stream>>>(ebuf, bcount, nb, E, N, rowptr, csr);

    // ---- layer 1 aggregation ----
    k_agg<64, 8><<<aggBlocks, 256, 0, stream>>>(hA, asb, adb, b1, rowptr, csr, N, 64, fB, 0);
    // ---- layer 2 GEMM ----
    k_gemm<64><<<gemmBlocks, 256, 0, stream>>>(fB, W2, a2s, a2d, N, 64, hA, asb, adb);
    // ---- layer 2 aggregation fused with layer-3 GEMM ----
    k_aggf<<<aggBlocks, 256, 0, stream>>>(hA, asb, adb, b2, rowptr, csr, N, W3,
                                          a3s, a3d, hC, asb3, adb3);
    // ---- layer 3 aggregation + log_softmax ----
    k_agg<16, 4><<<aggBlocks, 256, 0, stream>>>(hC, asb3, adb3, b3, rowptr, csr,
                                                N, 10, (float*)d_out, 1);
}

// Round 15
// 335.592 us; speedup vs baseline: 1.0013x; 1.0013x over previous
//
#include <hip/hip_runtime.h>
#include <math.h>
#include <type_traits>

// ---------------------------------------------------------------------------
// NodeClsGAT: 3-layer GATConv (single head, PyG defaults) on MI355X.
// CSR build via 2-level bucket sort (R2; bscan folded into bscatter/bcsr R14).
// GEMM via MFMA 16x16x32_f16 (R10); gemm1 fused with hist (R13).
// k_agg: R10 two-phase. k_aggf (agg2+gemm3 fused, R14) REWORKED in R15:
// R14 had 4.0M LDS bank conflicts (w3l stride 10 -> 8-way) and 4x-duplicated
// matvec. R15: stride 11 (2-way = free), alphas via precomputed w3s=W3@a3s /
// w3d=W3@a3d (folded into k_hist_gemm), pt matvec sliced across the 4 groups.
// ---------------------------------------------------------------------------

#define NEG_SLOPE 0.2f
#define BKT_BITS 9          // 512 nodes per bucket; supports N <= 262144
#define BKT_SZ   512
#define PACK_SRC_BITS 20    // src < 2^20 (N = 100000)

typedef _Float16 h8v __attribute__((ext_vector_type(8)));
typedef _Float16 h4v __attribute__((ext_vector_type(4)));
typedef float f4v __attribute__((ext_vector_type(4)));

// ---------------- pass B — rank-scatter packed records into buckets -----
__global__ __launch_bounds__(1024) void k_bscatter(const int* __restrict__ src,
                                                   const int* __restrict__ dst, int E,
                                                   int nb,
                                                   const int* __restrict__ bcount,
                                                   int* __restrict__ gcur,
                                                   int* __restrict__ ebuf) {
    __shared__ int lc[BKT_SZ];
    __shared__ int gb[BKT_SZ];
    __shared__ int sc[BKT_SZ];
    int t = threadIdx.x;
    for (int i = t; i < nb; i += 1024) lc[i] = 0;
    __syncthreads();
    int base = blockIdx.x * 8192;
    int bkt[8], rnk[8], pk[8];
#pragma unroll
    for (int j = 0; j < 8; j++) {
        int i = base + j * 1024 + t;
        bkt[j] = -1;
        if (i < E) {
            int d = dst[i];
            int s = src[i];
            int b = d >> BKT_BITS;
            bkt[j] = b;
            rnk[j] = atomicAdd(&lc[b], 1);
            pk[j] = ((d & (BKT_SZ - 1)) << PACK_SRC_BITS) | s;
        }
    }
    __syncthreads();
    if (t < BKT_SZ) sc[t] = (t < nb) ? bcount[t] : 0;
    __syncthreads();
    for (int o = 1; o < BKT_SZ; o <<= 1) {
        int tv = (t < BKT_SZ && t >= o) ? sc[t - o] : 0;
        __syncthreads();
        if (t < BKT_SZ) sc[t] += tv;
        __syncthreads();
    }
    for (int b = t; b < nb; b += 1024)
        if (lc[b]) gb[b] = (sc[b] - bcount[b]) + atomicAdd(&gcur[b], lc[b]);
    __syncthreads();
#pragma unroll
    for (int j = 0; j < 8; j++)
        if (bkt[j] >= 0) ebuf[gb[bkt[j]] + rnk[j]] = pk[j];
}

// ---------------- pass C — per-bucket CSR finalize ----------------------
__global__ __launch_bounds__(512) void k_bcsr(const int* __restrict__ ebuf,
                                              const int* __restrict__ bcount, int nb,
                                              int E, int N,
                                              int* __restrict__ rowptr,
                                              int* __restrict__ csr) {
    __shared__ int cnt[BKT_SZ];
    __shared__ int sm[BKT_SZ];
    int b = blockIdx.x;
    int t = threadIdx.x;
    sm[t] = (t < nb) ? bcount[t] : 0;
    __syncthreads();
    for (int o = 1; o < BKT_SZ; o <<= 1) {
        int tv = (t >= o) ? sm[t - o] : 0;
        __syncthreads();
        sm[t] += tv;
        __syncthreads();
    }
    int e1 = sm[b];
    int e0 = e1 - bcount[b];
    if (b == 0 && t == 0) rowptr[N] = E + N;
    __syncthreads();

    int n0 = b << BKT_BITS;
    int nn = min(BKT_SZ, N - n0);
    cnt[t] = 0;
    __syncthreads();
    for (int i = e0 + t; i < e1; i += BKT_SZ)
        atomicAdd(&cnt[ebuf[i] >> PACK_SRC_BITS], 1);
    __syncthreads();
    int v = cnt[t] + (t < nn ? 1 : 0);
    sm[t] = v;
    __syncthreads();
    for (int o = 1; o < BKT_SZ; o <<= 1) {
        int tv = (t >= o) ? sm[t - o] : 0;
        __syncthreads();
        sm[t] += tv;
        __syncthreads();
    }
    int excl = sm[t] - v;
    int cb = e0 + n0;
    if (t < nn) {
        rowptr[n0 + t] = cb + excl;
        csr[cb + excl] = n0 + t;
    }
    cnt[t] = excl + 1;
    __syncthreads();
    for (int i = e0 + t; i < e1; i += BKT_SZ) {
        int p = ebuf[i];
        int dl = p >> PACK_SRC_BITS;
        int pos = atomicAdd(&cnt[dl], 1);
        csr[cb + pos] = p & ((1 << PACK_SRC_BITS) - 1);
    }
}

// ---------------- GEMM body (FP=64, Freal=64) via MFMA, inlinable ----------
__device__ __forceinline__ void gemm64_body(
    int bid, int nblocks, const float* __restrict__ X, const float* __restrict__ W,
    const float* __restrict__ a_s, const float* __restrict__ a_d, int N,
    _Float16* __restrict__ H, float* __restrict__ asb, float* __restrict__ adb) {
    constexpr int NT = 4;
    int lane = threadIdx.x & 63;
    int quad = lane >> 4;
    int c16 = lane & 15;

    h8v bf[NT][2];
    float asv[NT], adv[NT];
#pragma unroll
    for (int nt = 0; nt < NT; nt++) {
        int n = nt * 16 + c16;
        asv[nt] = a_s[n];
        adv[nt] = a_d[n];
#pragma unroll
        for (int kt = 0; kt < 2; kt++)
#pragma unroll
            for (int j = 0; j < 8; j++) {
                int k = kt * 32 + quad * 8 + j;
                bf[nt][kt][j] = (_Float16)W[k * 64 + n];
            }
    }

    int wid = (bid * 256 + (int)threadIdx.x) >> 6;
    int nw = (nblocks * 256) >> 6;
    int ntile = (N + 15) >> 4;

    for (int t = wid; t < ntile; t += nw) {
        int m0 = t << 4;
        int row = m0 + c16;
        const float* xr = X + (size_t)min(row, N - 1) * 64;
        h8v af[2];
#pragma unroll
        for (int kt = 0; kt < 2; kt++) {
            f4v x0 = *(const f4v*)(xr + kt * 32 + quad * 8);
            f4v x1 = *(const f4v*)(xr + kt * 32 + quad * 8 + 4);
#pragma unroll
            for (int j = 0; j < 4; j++) {
                af[kt][j] = (_Float16)x0[j];
                af[kt][4 + j] = (_Float16)x1[j];
            }
        }
        f4v c[NT];
#pragma unroll
        for (int nt = 0; nt < NT; nt++) c[nt] = (f4v){0.f, 0.f, 0.f, 0.f};
#pragma unroll
        for (int kt = 0; kt < 2; kt++)
#pragma unroll
            for (int nt = 0; nt < NT; nt++)
                c[nt] = __builtin_amdgcn_mfma_f32_16x16x32_f16(af[kt], bf[nt][kt],
                                                               c[nt], 0, 0, 0);
#pragma unroll
        for (int reg = 0; reg < 4; reg++) {
            int r = m0 + quad * 4 + reg;
            if (r < N) {
#pragma unroll
                for (int nt = 0; nt < NT; nt++)
                    H[(size_t)r * 64 + nt * 16 + c16] = (_Float16)c[nt][reg];
            }
        }
        float ps[4], pd[4];
#pragma unroll
        for (int reg = 0; reg < 4; reg++) {
            ps[reg] = 0.f;
            pd[reg] = 0.f;
#pragma unroll
            for (int nt = 0; nt < NT; nt++) {
                ps[reg] = fmaf(c[nt][reg], asv[nt], ps[reg]);
                pd[reg] = fmaf(c[nt][reg], adv[nt], pd[reg]);
            }
        }
        for (int o = 1; o < 16; o <<= 1) {
#pragma unroll
            for (int reg = 0; reg < 4; reg++) {
                ps[reg] += __shfl_xor(ps[reg], o, 64);
                pd[reg] += __shfl_xor(pd[reg], o, 64);
            }
        }
        if (c16 == 0) {
#pragma unroll
            for (int reg = 0; reg < 4; reg++) {
                int r = m0 + quad * 4 + reg;
                if (r < N) {
                    asb[r] = ps[reg];
                    adb[r] = pd[reg];
                }
            }
        }
    }
}

// ---------------- fused: bucket histogram + layer-1 GEMM + W3 folds --------
// Blocks [0,histBlocks): dst histogram (block 0 also computes w3s=W3@a3s,
// w3d=W3@a3d for k_aggf's alpha epilogue); the rest: gemm1 (x@W1).
__global__ __launch_bounds__(256) void k_hist_gemm(
    const int* __restrict__ dst, int E, int nb, int* __restrict__ bcount,
    int histBlocks,
    const float* __restrict__ X, const float* __restrict__ W,
    const float* __restrict__ a_s, const float* __restrict__ a_d, int N,
    _Float16* __restrict__ H, float* __restrict__ asb, float* __restrict__ adb,
    const float* __restrict__ W3, const float* __restrict__ a3s,
    const float* __restrict__ a3d, float* __restrict__ w3s,
    float* __restrict__ w3d) {
    __shared__ int h[BKT_SZ];
    int bid = blockIdx.x;
    if (bid < histBlocks) {
        if (bid == 0 && threadIdx.x < 64) {
            int k = threadIdx.x;
            float s = 0.f, d = 0.f;
#pragma unroll
            for (int t = 0; t < 10; t++) {
                float w = W3[k * 10 + t];
                s = fmaf(w, a3s[t], s);
                d = fmaf(w, a3d[t], d);
            }
            w3s[k] = s;
            w3d[k] = d;
        }
        for (int i = threadIdx.x; i < nb; i += 256) h[i] = 0;
        __syncthreads();
        for (int i = bid * 256 + threadIdx.x; i < E; i += histBlocks * 256)
            atomicAdd(&h[dst[i] >> BKT_BITS], 1);
        __syncthreads();
        for (int i = threadIdx.x; i < nb; i += 256)
            if (h[i]) atomicAdd(&bcount[i], h[i]);
    } else {
        gemm64_body(bid - histBlocks, (int)gridDim.x - histBlocks, X, W, a_s, a_d,
                    N, H, asb, adb);
    }
}

// ---------------- standalone GEMM (layer 2) --------------------------------
template <int FP>
__global__ __launch_bounds__(256) void k_gemm(
    const float* __restrict__ X, const float* __restrict__ W,
    const float* __restrict__ a_s, const float* __restrict__ a_d,
    int N, int Freal,
    _Float16* __restrict__ H, float* __restrict__ asb, float* __restrict__ adb) {
    constexpr int NT = FP / 16;
    int lane = threadIdx.x & 63;
    int quad = lane >> 4;
    int c16 = lane & 15;

    h8v bf[NT][2];
    float asv[NT], adv[NT];
#pragma unroll
    for (int nt = 0; nt < NT; nt++) {
        int n = nt * 16 + c16;
        bool ok = (n < Freal);
        asv[nt] = ok ? a_s[n] : 0.f;
        adv[nt] = ok ? a_d[n] : 0.f;
#pragma unroll
        for (int kt = 0; kt < 2; kt++)
#pragma unroll
            for (int j = 0; j < 8; j++) {
                int k = kt * 32 + quad * 8 + j;
                bf[nt][kt][j] = (_Float16)(ok ? W[k * Freal + n] : 0.f);
            }
    }

    int wid = (blockIdx.x * blockDim.x + threadIdx.x) >> 6;
    int nw = (gridDim.x * blockDim.x) >> 6;
    int ntile = (N + 15) >> 4;

    for (int t = wid; t < ntile; t += nw) {
        int m0 = t << 4;
        int row = m0 + c16;
        const float* xr = X + (size_t)min(row, N - 1) * 64;
        h8v af[2];
#pragma unroll
        for (int kt = 0; kt < 2; kt++) {
            f4v x0 = *(const f4v*)(xr + kt * 32 + quad * 8);
            f4v x1 = *(const f4v*)(xr + kt * 32 + quad * 8 + 4);
#pragma unroll
            for (int j = 0; j < 4; j++) {
                af[kt][j] = (_Float16)x0[j];
                af[kt][4 + j] = (_Float16)x1[j];
            }
        }
        f4v c[NT];
#pragma unroll
        for (int nt = 0; nt < NT; nt++) c[nt] = (f4v){0.f, 0.f, 0.f, 0.f};
#pragma unroll
        for (int kt = 0; kt < 2; kt++)
#pragma unroll
            for (int nt = 0; nt < NT; nt++)
                c[nt] = __builtin_amdgcn_mfma_f32_16x16x32_f16(af[kt], bf[nt][kt],
                                                               c[nt], 0, 0, 0);
#pragma unroll
        for (int reg = 0; reg < 4; reg++) {
            int r = m0 + quad * 4 + reg;
            if (r < N) {
#pragma unroll
                for (int nt = 0; nt < NT; nt++)
                    H[(size_t)r * FP + nt * 16 + c16] = (_Float16)c[nt][reg];
            }
        }
        float ps[4], pd[4];
#pragma unroll
        for (int reg = 0; reg < 4; reg++) {
            ps[reg] = 0.f;
            pd[reg] = 0.f;
#pragma unroll
            for (int nt = 0; nt < NT; nt++) {
                ps[reg] = fmaf(c[nt][reg], asv[nt], ps[reg]);
                pd[reg] = fmaf(c[nt][reg], adv[nt], pd[reg]);
            }
        }
        for (int o = 1; o < 16; o <<= 1) {
#pragma unroll
            for (int reg = 0; reg < 4; reg++) {
                ps[reg] += __shfl_xor(ps[reg], o, 64);
                pd[reg] += __shfl_xor(pd[reg], o, 64);
            }
        }
        if (c16 == 0) {
#pragma unroll
            for (int reg = 0; reg < 4; reg++) {
                int r = m0 + quad * 4 + reg;
                if (r < N) {
                    asb[r] = ps[reg];
                    adb[r] = pd[reg];
                }
            }
        }
    }
}

// ---------------- slow-path agg (R4-proven, whole wave, any deg) -----------
template <int FP>
__device__ __forceinline__ void agg_slow(
    int node, const _Float16* __restrict__ H, const float* __restrict__ asb,
    const float* __restrict__ adb, const float* __restrict__ bias,
    const int* __restrict__ rowptr, const int* __restrict__ csr,
    int N, int Freal, float* __restrict__ out, int mode, int lane) {
    if (node >= N) return;
    int start = rowptr[node];
    int end = rowptr[node + 1];
    float ad = adb[node];
    int lf = lane & (FP - 1);
    const float NEG_INF = -__builtin_inff();

    float m = NEG_INF;
    for (int base = start; base < end; base += 64) {
        int i = base + lane;
        if (i < end) {
            float t = asb[csr[i]] + ad;
            float e = (t > 0.f) ? t : NEG_SLOPE * t;
            m = fmaxf(m, e);
        }
    }
    for (int o = 32; o > 0; o >>= 1) m = fmaxf(m, __shfl_xor(m, o, 64));
    float dsum = 0.f, acc = 0.f;
    for (int base = start; base < end; base += 64) {
        int i = base + lane;
        int cnt = min(64, end - base);
        int s = 0;
        float p = 0.f;
        if (i < end) {
            s = csr[i];
            float t = asb[s] + ad;
            float e = (t > 0.f) ? t : NEG_SLOPE * t;
            p = __expf(e - m);
        }
        dsum += p;
        for (int j = 0; j < cnt; j++) {
            float pj = __shfl(p, j, 64);
            int sj = __shfl(s, j, 64);
            acc = fmaf(pj, (float)H[(size_t)sj * FP + lf], acc);
        }
    }
    for (int o = 32; o > 0; o >>= 1) dsum += __shfl_xor(dsum, o, 64);

    float b = (lf < Freal) ? bias[lf] : 0.f;
    float z = acc / dsum + b;
    if (mode == 0) {
        if (lane < FP) out[(size_t)node * FP + lane] = fmaxf(z, 0.f);
    } else {
        float zz = (lane < Freal) ? z : NEG_INF;
        float zm = zz;
        for (int o = 32; o > 0; o >>= 1) zm = fmaxf(zm, __shfl_xor(zm, o, 64));
        float ez = (lane < Freal) ? __expf(zz - zm) : 0.f;
        float es = ez;
        for (int o = 32; o > 0; o >>= 1) es += __shfl_xor(es, o, 64);
        if (lane < Freal) out[(size_t)node * Freal + lane] = zz - zm - __logf(es);
    }
}

// slow-path variant returning z = agg + bias (no relu, no store); FP=64 only.
__device__ __forceinline__ float agg_slow_z64(
    int node, const _Float16* __restrict__ H, const float* __restrict__ asb,
    const float* __restrict__ adb, const float* __restrict__ bias,
    const int* __restrict__ rowptr, const int* __restrict__ csr, int lane) {
    int start = rowptr[node];
    int end = rowptr[node + 1];
    float ad = adb[node];
    const float NEG_INF = -__builtin_inff();

    float m = NEG_INF;
    for (int base = start; base < end; base += 64) {
        int i = base + lane;
        if (i < end) {
            float t = asb[csr[i]] + ad;
            float e = (t > 0.f) ? t : NEG_SLOPE * t;
            m = fmaxf(m, e);
        }
    }
    for (int o = 32; o > 0; o >>= 1) m = fmaxf(m, __shfl_xor(m, o, 64));
    float dsum = 0.f, acc = 0.f;
    for (int base = start; base < end; base += 64) {
        int i = base + lane;
        int cnt = min(64, end - base);
        int s = 0;
        float p = 0.f;
        if (i < end) {
            s = csr[i];
            float t = asb[s] + ad;
            float e = (t > 0.f) ? t : NEG_SLOPE * t;
            p = __expf(e - m);
        }
        dsum += p;
        for (int j = 0; j < cnt; j++) {
            float pj = __shfl(p, j, 64);
            int sj = __shfl(s, j, 64);
            acc = fmaf(pj, (float)H[(size_t)sj * 64 + lane], acc);
        }
    }
    for (int o = 32; o > 0; o >>= 1) dsum += __shfl_xor(dsum, o, 64);
    return acc / dsum + bias[lane];
}

// ---------------- Aggregation: dual-node wave, vector gather (R10) ---------
template <int FP, int W>
__global__ __launch_bounds__(256) void k_agg(
    const _Float16* __restrict__ H, const float* __restrict__ asb,
    const float* __restrict__ adb, const float* __restrict__ bias,
    const int* __restrict__ rowptr, const int* __restrict__ csr,
    int N, int Freal, float* __restrict__ out, int mode) {
    constexpr int LPR = FP / W;    // lanes per row (within a half)
    constexpr int GRPH = 32 / LPR; // rows in flight per half
    using vecW = typename std::conditional<W == 8, h8v, h4v>::type;
    int lane = threadIdx.x & 63;
    int half = lane >> 5;
    int li = lane & 31;
    int wid = (blockIdx.x * blockDim.x + threadIdx.x) >> 6;
    int nA = 2 * wid;
    if (nA >= N) return;
    int n = nA + half;
    bool valid = (n < N);
    int start = 0, end = 0;
    float ad = 0.f;
    if (valid) {
        start = rowptr[n];
        end = rowptr[n + 1];
        ad = adb[n];
    }
    int deg = end - start;
    int degm = max(deg, __shfl_xor(deg, 32, 64));

    const float NEG_INF = -__builtin_inff();

    if (degm <= 32) {
        int g = li / LPR;
        int fl = li % LPR;
        int s = 0;
        float e = NEG_INF;
        if (li < deg) {
            s = csr[start + li];
            float t = asb[s] + ad;
            e = (t > 0.f) ? t : NEG_SLOPE * t;
        }
        float m = e;
        for (int o = 16; o > 0; o >>= 1) m = fmaxf(m, __shfl_xor(m, o, 64));
        float p = (li < deg) ? __expf(e - m) : 0.f;
        float dsum = p;
        for (int o = 16; o > 0; o >>= 1) dsum += __shfl_xor(dsum, o, 64);

        float acc[W];
#pragma unroll
        for (int c = 0; c < W; c++) acc[c] = 0.f;
#pragma unroll 4
        for (int jb = 0; jb < degm; jb += GRPH) {
            int gidx = half * 32 + jb + g;
            float pj = __shfl(p, gidx, 64);
            int sj = __shfl(s, gidx, 64);
            vecW r = ((const vecW*)(H + (size_t)sj * FP))[fl];
#pragma unroll
            for (int c = 0; c < W; c++) acc[c] = fmaf(pj, (float)r[c], acc[c]);
        }
        for (int o = LPR; o < 32; o <<= 1) {
#pragma unroll
            for (int c = 0; c < W; c++) acc[c] += __shfl_xor(acc[c], o, 64);
        }
        float inv = 1.f / dsum;
        int fbase = fl * W;

        if (mode == 0) {
            if (valid && li < LPR) {
                float z[W];
#pragma unroll
                for (int c = 0; c < W; c++)
                    z[c] = fmaxf(fmaf(acc[c], inv, bias[fbase + c]), 0.f);
                float4* op = (float4*)(out + (size_t)n * FP + fbase);
#pragma unroll
                for (int q = 0; q < W / 4; q++)
                    op[q] = make_float4(z[4 * q], z[4 * q + 1], z[4 * q + 2],
                                        z[4 * q + 3]);
            }
        } else {
            float zc[W];
#pragma unroll
            for (int c = 0; c < W; c++) {
                int f = fbase + c;
                zc[c] = (f < Freal) ? fmaf(acc[c], inv, bias[f]) : NEG_INF;
            }
            float vm = zc[0];
#pragma unroll
            for (int c = 1; c < W; c++) vm = fmaxf(vm, zc[c]);
            for (int o = 1; o < LPR; o <<= 1) vm = fmaxf(vm, __shfl_xor(vm, o, 64));
            float es = 0.f;
#pragma unroll
            for (int c = 0; c < W; c++) es += __expf(zc[c] - vm);
            for (int o = 1; o < LPR; o <<= 1) es += __shfl_xor(es, o, 64);
            float ls = __logf(es);
            if (valid && li < LPR) {
#pragma unroll
                for (int c = 0; c < W; c++) {
                    int f = fbase + c;
                    if (f < Freal) out[(size_t)n * Freal + f] = zc[c] - vm - ls;
                }
            }
        }
    } else {
        agg_slow<FP>(nA, H, asb, adb, bias, rowptr, csr, N, Freal, out, mode, lane);
        agg_slow<FP>(nA + 1, H, asb, adb, bias, rowptr, csr, N, Freal, out, mode, lane);
    }
}

// ---------------- Fused agg2 + gemm3: k_aggf (R15 rework) ------------------
// Dual-node structure as k_agg<64,8>. Epilogue: alphas via w3s/w3d folds
// (16 FMA + 6 shfl), h3 matvec SLICED across the 4 groups (slices 3/3/2/2 of
// the 10 outputs; <=24 FMA + 9 shfl/lane); w3l stride 11 (2-way = free).
__global__ __launch_bounds__(256) void k_aggf(
    const _Float16* __restrict__ H, const float* __restrict__ asb,
    const float* __restrict__ adb, const float* __restrict__ bias,  // b2
    const int* __restrict__ rowptr, const int* __restrict__ csr, int N,
    const float* __restrict__ W3, const float* __restrict__ a3s,
    const float* __restrict__ a3d, const float* __restrict__ w3s,
    const float* __restrict__ w3d,
    _Float16* __restrict__ H3, float* __restrict__ asb3,
    float* __restrict__ adb3) {
    constexpr int LPR = 8, GRPH = 4;
    __shared__ float w3l[64 * 11];  // stride 11: 8*11=88 = 24 mod 32 -> 2-way
    __shared__ float w3sl[64], w3dl[64];
    __shared__ float a3sl[10], a3dl[10];
    for (int i = threadIdx.x; i < 64 * 11; i += 256)
        w3l[i] = (i % 11 < 10) ? W3[(i / 11) * 10 + (i % 11)] : 0.f;
    if (threadIdx.x < 64) {
        w3sl[threadIdx.x] = w3s[threadIdx.x];
        w3dl[threadIdx.x] = w3d[threadIdx.x];
    }
    if (threadIdx.x < 10) {
        a3sl[threadIdx.x] = a3s[threadIdx.x];
        a3dl[threadIdx.x] = a3d[threadIdx.x];
    }
    __syncthreads();  // before any early return

    int lane = threadIdx.x & 63;
    int half = lane >> 5;
    int li = lane & 31;
    int wid = (blockIdx.x * blockDim.x + threadIdx.x) >> 6;
    int nA = 2 * wid;
    if (nA >= N) return;
    int n = nA + half;
    bool valid = (n < N);
    int start = 0, end = 0;
    float ad = 0.f;
    if (valid) {
        start = rowptr[n];
        end = rowptr[n + 1];
        ad = adb[n];
    }
    int deg = end - start;
    int degm = max(deg, __shfl_xor(deg, 32, 64));

    const float NEG_INF = -__builtin_inff();

    if (degm <= 32) {
        int g = li / LPR;
        int fl = li % LPR;
        int s = 0;
        float e = NEG_INF;
        if (li < deg) {
            s = csr[start + li];
            float t = asb[s] + ad;
            e = (t > 0.f) ? t : NEG_SLOPE * t;
        }
        float m = e;
        for (int o = 16; o > 0; o >>= 1) m = fmaxf(m, __shfl_xor(m, o, 64));
        float p = (li < deg) ? __expf(e - m) : 0.f;
        float dsum = p;
        for (int o = 16; o > 0; o >>= 1) dsum += __shfl_xor(dsum, o, 64);

        float acc[8];
#pragma unroll
        for (int c = 0; c < 8; c++) acc[c] = 0.f;
#pragma unroll 4
        for (int jb = 0; jb < degm; jb += GRPH) {
            int gidx = half * 32 + jb + g;
            float pj = __shfl(p, gidx, 64);
            int sj = __shfl(s, gidx, 64);
            h8v r = ((const h8v*)(H + (size_t)sj * 64))[fl];
#pragma unroll
            for (int c = 0; c < 8; c++) acc[c] = fmaf(pj, (float)r[c], acc[c]);
        }
        for (int o = LPR; o < 32; o <<= 1) {
#pragma unroll
            for (int c = 0; c < 8; c++) acc[c] += __shfl_xor(acc[c], o, 64);
        }
        float inv = 1.f / dsum;
        int fbase = fl * 8;
        float z[8];
#pragma unroll
        for (int c = 0; c < 8; c++)
            z[c] = fmaxf(fmaf(acc[c], inv, bias[fbase + c]), 0.f);
        // alphas: s3 = relu(z) . (W3@a3s) — no pt needed
        float s3 = 0.f, d3 = 0.f;
#pragma unroll
        for (int c = 0; c < 8; c++) {
            s3 = fmaf(z[c], w3sl[fbase + c], s3);
            d3 = fmaf(z[c], w3dl[fbase + c], d3);
        }
        for (int o = 1; o < 8; o <<= 1) {
            s3 += __shfl_xor(s3, o, 64);
            d3 += __shfl_xor(d3, o, 64);
        }
        if (valid && li == 0) {
            asb3[n] = s3;
            adb3[n] = d3;
        }
        // h3 matvec sliced across groups: g0:t=0..2, g1:3..5, g2:6..7, g3:8..9
        int t0 = (g < 2) ? g * 3 : 2 + g * 2;  // 0,3,6,8
        int tn = (g < 2) ? 3 : 2;
        float pt[3] = {0.f, 0.f, 0.f};
#pragma unroll
        for (int c = 0; c < 8; c++) {
            const float* wr = &w3l[(fbase + c) * 11 + t0];
            float zv = z[c];
#pragma unroll
            for (int tt = 0; tt < 3; tt++) pt[tt] = fmaf(zv, wr[tt], pt[tt]);
        }
        for (int o = 1; o < 8; o <<= 1) {
#pragma unroll
            for (int tt = 0; tt < 3; tt++) pt[tt] += __shfl_xor(pt[tt], o, 64);
        }
        if (valid && fl == 0) {
            if (g == 3) {
                h8v hv = {};  // slots 8,9 = data; 10..15 = zero pad
                hv[0] = (_Float16)pt[0];
                hv[1] = (_Float16)pt[1];
                *(h8v*)(H3 + (size_t)n * 16 + 8) = hv;
            } else {
                for (int tt = 0; tt < tn; tt++)
                    H3[(size_t)n * 16 + t0 + tt] = (_Float16)pt[tt];
            }
        }
    } else {
        // rare slow path: whole-wave per node
        for (int q = 0; q < 2; q++) {
            int node = nA + q;
            if (node >= N) continue;
            float z = agg_slow_z64(node, H, asb, adb, bias, rowptr, csr, lane);
            z = fmaxf(z, 0.f);
            float pt[10];
            const float* wr = &w3l[lane * 11];
#pragma unroll
            for (int t = 0; t < 10; t++) pt[t] = z * wr[t];
            for (int o = 1; o < 64; o <<= 1) {
#pragma unroll
                for (int t = 0; t < 10; t++) pt[t] += __shfl_xor(pt[t], o, 64);
            }
            if (lane == 0) {
                h8v hv;
#pragma unroll
                for (int j = 0; j < 8; j++) hv[j] = (_Float16)pt[j];
                *(h8v*)(H3 + (size_t)node * 16) = hv;
                h8v hv2 = {};
                hv2[0] = (_Float16)pt[8];
                hv2[1] = (_Float16)pt[9];
                *(h8v*)(H3 + (size_t)node * 16 + 8) = hv2;
                float s3 = 0.f, d3 = 0.f;
#pragma unroll
                for (int t = 0; t < 10; t++) {
                    s3 = fmaf(pt[t], a3sl[t], s3);
                    d3 = fmaf(pt[t], a3dl[t], d3);
                }
                asb3[node] = s3;
                adb3[node] = d3;
            }
        }
    }
}

// ---------------------------------------------------------------------------
extern "C" void kernel_launch(void* const* d_in, const int* in_sizes, int n_in,
                              void* d_out, int out_size, void* d_ws, size_t ws_size,
                              hipStream_t stream) {
    const float* x = (const float*)d_in[0];
    const int* ei = (const int*)d_in[1];
    const float* W1 = (const float*)d_in[2];
    const float* a1s = (const float*)d_in[3];
    const float* a1d = (const float*)d_in[4];
    const float* b1 = (const float*)d_in[5];
    const float* W2 = (const float*)d_in[6];
    const float* a2s = (const float*)d_in[7];
    const float* a2d = (const float*)d_in[8];
    const float* b2 = (const float*)d_in[9];
    const float* W3 = (const float*)d_in[10];
    const float* a3s = (const float*)d_in[11];
    const float* a3d = (const float*)d_in[12];
    const float* b3 = (const float*)d_in[13];

    const int N = in_sizes[0] / 64;
    const int E = in_sizes[1] / 2;
    const int Etot = E + N;
    const int nb = (N + BKT_SZ - 1) >> BKT_BITS;
    const int* srcv = ei;
    const int* dstv = ei + E;

    // workspace carve (256B aligned)
    size_t off = 0;
    char* base = (char*)d_ws;
    auto carve = [&](size_t bytes) -> void* {
        void* p = base + off;
        off = (off + bytes + 255) & ~(size_t)255;
        return p;
    };
    int* bcount = (int*)carve((size_t)(nb + 1) * 4);
    int* gcur = (int*)carve((size_t)nb * 4);
    int* rowptr = (int*)carve((size_t)(N + 1) * 4);
    int* csr = (int*)carve((size_t)Etot * 4);
    float* asb = (float*)carve((size_t)N * 4);
    float* adb = (float*)carve((size_t)N * 4);
    float* asb3 = (float*)carve((size_t)N * 4);
    float* adb3 = (float*)carve((size_t)N * 4);
    float* w3s = (float*)carve(64 * 4);
    float* w3d = (float*)carve(64 * 4);
    _Float16* hA = (_Float16*)carve((size_t)N * 64 * 2);  // fp16 H (layers 1,2)
    float* fB = (float*)carve((size_t)N * 64 * 4);        // fp32 agg1 out
    _Float16* hC = (_Float16*)carve((size_t)N * 16 * 2);  // fp16 H (layer 3)
    int* ebuf = (int*)carve((size_t)E * 4);

    const int aggBlocks = (N + 7) / 8;  // 4 waves/block, 2 nodes/wave
    const int gemmBlocks = 784;
    const int histBlocks = 512;

    // ---- CSR build (bucket sort) + layer-1 GEMM + W3 folds, fused ----
    hipMemsetAsync(bcount, 0, (size_t)nb * 4, stream);
    hipMemsetAsync(gcur, 0, (size_t)nb * 4, stream);
    k_hist_gemm<<<histBlocks + gemmBlocks, 256, 0, stream>>>(
        dstv, E, nb, bcount, histBlocks, x, W1, a1s, a1d, N, hA, asb, adb,
        W3, a3s, a3d, w3s, w3d);
    k_bscatter<<<(E + 8191) / 8192, 1024, 0, stream>>>(srcv, dstv, E, nb, bcount,
                                                       gcur, ebuf);
    k_bcsr<<<nb, BKT_SZ, 0, stream>>>(ebuf, bcount, nb, E, N, rowptr, csr);

    // ---- layer 1 aggregation ----
    k_agg<64, 8><<<aggBlocks, 256, 0, stream>>>(hA, asb, adb, b1, rowptr, csr, N, 64, fB, 0);
    // ---- layer 2 GEMM ----
    k_gemm<64><<<gemmBlocks, 256, 0, stream>>>(fB, W2, a2s, a2d, N, 64, hA, asb, adb);
    // ---- layer 2 aggregation fused with layer-3 GEMM ----
    k_aggf<<<aggBlocks, 256, 0, stream>>>(hA, asb, adb, b2, rowptr, csr, N, W3,
                                          a3s, a3d, w3s, w3d, hC, asb3, adb3);
    // ---- layer 3 aggregation + log_softmax ----
    k_agg<16, 4><<<aggBlocks, 256, 0, stream>>>(hC, asb3, adb3, b3, rowptr, csr,
                                                N, 10, (float*)d_out, 1);
}